// Round 2
// baseline (752.979 us; speedup 1.0000x reference)
//
#include <hip/hip_runtime.h>

#define BB 2
#define NN 20000
#define HH 128
#define EE 200000

typedef unsigned short u16;
typedef __attribute__((ext_vector_type(4))) float f32x4;
typedef __bf16 bf16x8 __attribute__((ext_vector_type(8)));

#define MFMA(a, b, c) __builtin_amdgcn_mfma_f32_16x16x32_bf16((a), (b), (c), 0, 0, 0)

__device__ __forceinline__ float bf2f(u16 u) {
    union { unsigned int i; float f; } v; v.i = ((unsigned int)u) << 16; return v.f;
}
__device__ __forceinline__ u16 f2bf(float f) {
    union { float f; unsigned int i; } v; v.f = f;
    unsigned int r = (v.i + 0x7FFFu + ((v.i >> 16) & 1u)) >> 16;
    return (u16)r;
}
// NaN-proof silu: tanh never returns inf for finite input
__device__ __forceinline__ float silu_f(float z) { return 0.5f * z * (1.f + tanhf(0.5f * z)); }

// ---------------- dtype detection ----------------
// If inputs are f32, the even u16 halves are low mantissa bits -> ~uniform
// bf16 exponent field. If inputs are bf16, even u16s are real ~N(0,1) values
// with exponent in [101,143] essentially always.
__global__ void detect_kernel(const u16* __restrict__ f, int* __restrict__ flag) {
    int tid = threadIdx.x;
    u16 v = f[tid * 2];
    int e = (v >> 7) & 0xFF;
    int ok = (e >= 101 && e <= 143) ? 1 : 0;
    __shared__ int cnt;
    if (tid == 0) cnt = 0;
    __syncthreads();
    atomicAdd(&cnt, ok);
    __syncthreads();
    if (tid == 0) *flag = (cnt < 200) ? 1 : 0;   // 1 => inputs are float32
}

// ---------------- canonicalize all float inputs to bf16 in ws ----------------
#define CTOT 5461776
struct P24 { const void* p[24]; };

__global__ __launch_bounds__(256) void canon_kernel(P24 ptrs, const int* __restrict__ flag,
                                                    u16* __restrict__ canon) {
    static const int off[25] = {
        0, 5120000, 5240000, 5260000, 5280000, 5312896, 5313024, 5329408,
        5329536, 5345920, 5346048, 5346176, 5346184, 5379080, 5379208, 5395592,
        5395720, 5412104, 5412232, 5412360, 5412368, 5445136, 5445264, 5461648,
        5461776 };
    static const int rsz[24] = {
        5120000, 120000, 20000, 20000,
        32896, 128, 16384, 128, 16384, 128, 128, 1,
        32896, 128, 16384, 128, 16384, 128, 128, 1,
        32768, 128, 16384, 128 };
    int i = blockIdx.x * 256 + threadIdx.x;
    if (i >= CTOT) return;
    int t = 0;
#pragma unroll 1
    while (i >= off[t + 1]) ++t;
    int j = i - off[t];
    u16 v;
    if (j >= rsz[t]) v = 0;
    else if (*flag) v = f2bf(((const float*)ptrs.p[t])[j]);
    else v = ((const u16*)ptrs.p[t])[j];
    canon[i] = v;
}

// ---------------- weight fragment permutation ----------------
// F[((kt*8+nt)*64+lane)*8 + j] = W[(kt*32+(lane>>4)*8+j)*128 + nt*16+(lane&15)]
__global__ void make_frag(const u16* __restrict__ W, u16* __restrict__ F) {
    int tid = blockIdx.x * 256 + threadIdx.x;
    int j = tid & 7, lane = (tid >> 3) & 63, nt = (tid >> 9) & 7, kt = tid >> 12;
    int k = kt * 32 + ((lane >> 4) * 8) + j;
    int n = nt * 16 + (lane & 15);
    F[tid] = W[k * 128 + n];
}

__global__ __launch_bounds__(256) void edge_kernel(
    const u16* __restrict__ feat, const u16* __restrict__ posit,
    const int* __restrict__ eidx,
    const u16* __restrict__ fW1, const u16* __restrict__ w1last, const u16* __restrict__ bias1,
    const u16* __restrict__ fW2, const u16* __restrict__ bias2,
    const u16* __restrict__ fP1, const u16* __restrict__ biasp1,
    const u16* __restrict__ wp2, const u16* __restrict__ biasp2,
    float* __restrict__ agg, float* __restrict__ pos_acc)
{
    const int tid = threadIdx.x;
    const int lane = tid & 63;
    const int wv = tid >> 6;
    const int row0 = blockIdx.x * 64;

    __shared__ u16 sA[64][136];   // h_src, later: messages (bf16)
    __shared__ u16 sB[64][136];   // h_dst, later: pos-hidden (bf16)
    __shared__ u16 sY[64][136];   // msg-hidden (bf16)
    __shared__ float sRel[64][3];
    __shared__ float sDist[64];
    __shared__ int sSrc[64], sDst[64], sBat[64];

    if (tid < 64) {
        int inst = row0 + tid;           // 0 .. B*E-1
        int b = inst / EE;
        int e = inst - b * EE;
        int s = eidx[e];
        int d = eidx[EE + e];
        sSrc[tid] = s; sDst[tid] = d; sBat[tid] = b;
        const u16* ps = posit + ((size_t)b * NN + s) * 3;
        const u16* pd = posit + ((size_t)b * NN + d) * 3;
        float dx = bf2f(ps[0]) - bf2f(pd[0]);
        float dy = bf2f(ps[1]) - bf2f(pd[1]);
        float dz = bf2f(ps[2]) - bf2f(pd[2]);
        sRel[tid][0] = dx; sRel[tid][1] = dy; sRel[tid][2] = dz;
        sDist[tid] = sqrtf(dx * dx + dy * dy + dz * dz);
    }
    __syncthreads();

    // gather h_src / h_dst : 4 threads per row, 64B each, uint4 loads
    {
        const int r = tid >> 2, part = tid & 3;
        const uint4* fs = (const uint4*)(feat + ((size_t)sBat[r] * NN + sSrc[r]) * HH);
        const uint4* fd = (const uint4*)(feat + ((size_t)sBat[r] * NN + sDst[r]) * HH);
        uint4* as = (uint4*)&sA[r][part * 32];
        uint4* ad = (uint4*)&sB[r][part * 32];
#pragma unroll
        for (int i = 0; i < 4; ++i) { as[i] = fs[part * 4 + i]; ad[i] = fd[part * 4 + i]; }
    }
    __syncthreads();

    const int nt0 = wv * 2;            // this wave owns n-tiles nt0, nt0+1
    const int mrow = lane & 15;        // A-frag row within tile
    const int kq = (lane >> 4) * 8;    // A/B-frag k offset
    const int crow = (lane >> 4) * 4;  // C row base within tile
    const int ccol = lane & 15;        // C col within tile

    f32x4 acc[4][2];
#pragma unroll
    for (int mt = 0; mt < 4; ++mt) {
        acc[mt][0] = (f32x4){0.f, 0.f, 0.f, 0.f};
        acc[mt][1] = (f32x4){0.f, 0.f, 0.f, 0.f};
    }

    // ----- msg layer 1 : [h_src | h_dst] @ W1[0:256]  (K=256) -----
#pragma unroll
    for (int kt = 0; kt < 8; ++kt) {
        const u16* Xb = (kt < 4) ? &sA[0][0] : &sB[0][0];
        const int kk = (kt & 3) * 32 + kq;
        bf16x8 bw0 = *(const bf16x8*)(fW1 + (size_t)(((kt * 8 + nt0) * 64 + lane) * 8));
        bf16x8 bw1 = *(const bf16x8*)(fW1 + (size_t)(((kt * 8 + nt0 + 1) * 64 + lane) * 8));
#pragma unroll
        for (int mt = 0; mt < 4; ++mt) {
            bf16x8 a = *(const bf16x8*)(Xb + (mt * 16 + mrow) * 136 + kk);
            acc[mt][0] = MFMA(a, bw0, acc[mt][0]);
            acc[mt][1] = MFMA(a, bw1, acc[mt][1]);
        }
    }
    // epilogue: + dist*W1[256] + b1, silu -> sY
#pragma unroll
    for (int mt = 0; mt < 4; ++mt) {
#pragma unroll
        for (int n2 = 0; n2 < 2; ++n2) {
            const int col = (nt0 + n2) * 16 + ccol;
            const float wl = bf2f(w1last[col]);
            const float bb = bf2f(bias1[col]);
#pragma unroll
            for (int r = 0; r < 4; ++r) {
                const int row = mt * 16 + crow + r;
                float z = acc[mt][n2][r] + sDist[row] * wl + bb;
                sY[row][col] = f2bf(silu_f(z));
            }
        }
    }
    __syncthreads();

    // ----- msg layer 2 : sY @ W2 + b2 = messages (K=128) -----
#pragma unroll
    for (int mt = 0; mt < 4; ++mt) {
        acc[mt][0] = (f32x4){0.f, 0.f, 0.f, 0.f};
        acc[mt][1] = (f32x4){0.f, 0.f, 0.f, 0.f};
    }
#pragma unroll
    for (int kt = 0; kt < 4; ++kt) {
        const int kk = kt * 32 + kq;
        bf16x8 bw0 = *(const bf16x8*)(fW2 + (size_t)(((kt * 8 + nt0) * 64 + lane) * 8));
        bf16x8 bw1 = *(const bf16x8*)(fW2 + (size_t)(((kt * 8 + nt0 + 1) * 64 + lane) * 8));
#pragma unroll
        for (int mt = 0; mt < 4; ++mt) {
            bf16x8 a = *(const bf16x8*)(&sY[0][0] + (mt * 16 + mrow) * 136 + kk);
            acc[mt][0] = MFMA(a, bw0, acc[mt][0]);
            acc[mt][1] = MFMA(a, bw1, acc[mt][1]);
        }
    }
    // epilogue: messages -> atomic scatter into agg + bf16 copy into sA
#pragma unroll
    for (int mt = 0; mt < 4; ++mt) {
#pragma unroll
        for (int n2 = 0; n2 < 2; ++n2) {
            const int col = (nt0 + n2) * 16 + ccol;
            const float bb = bf2f(bias2[col]);
#pragma unroll
            for (int r = 0; r < 4; ++r) {
                const int row = mt * 16 + crow + r;
                float m = acc[mt][n2][r] + bb;
                sA[row][col] = f2bf(m);
                unsafeAtomicAdd(&agg[((size_t)sBat[row] * NN + sDst[row]) * HH + col], m);
            }
        }
    }
    __syncthreads();

    // ----- pos layer 1 : silu(messages @ P1 + bp1) -> sB (K=128) -----
#pragma unroll
    for (int mt = 0; mt < 4; ++mt) {
        acc[mt][0] = (f32x4){0.f, 0.f, 0.f, 0.f};
        acc[mt][1] = (f32x4){0.f, 0.f, 0.f, 0.f};
    }
#pragma unroll
    for (int kt = 0; kt < 4; ++kt) {
        const int kk = kt * 32 + kq;
        bf16x8 bw0 = *(const bf16x8*)(fP1 + (size_t)(((kt * 8 + nt0) * 64 + lane) * 8));
        bf16x8 bw1 = *(const bf16x8*)(fP1 + (size_t)(((kt * 8 + nt0 + 1) * 64 + lane) * 8));
#pragma unroll
        for (int mt = 0; mt < 4; ++mt) {
            bf16x8 a = *(const bf16x8*)(&sA[0][0] + (mt * 16 + mrow) * 136 + kk);
            acc[mt][0] = MFMA(a, bw0, acc[mt][0]);
            acc[mt][1] = MFMA(a, bw1, acc[mt][1]);
        }
    }
#pragma unroll
    for (int mt = 0; mt < 4; ++mt) {
#pragma unroll
        for (int n2 = 0; n2 < 2; ++n2) {
            const int col = (nt0 + n2) * 16 + ccol;
            const float bb = bf2f(biasp1[col]);
#pragma unroll
            for (int r = 0; r < 4; ++r) {
                const int row = mt * 16 + crow + r;
                sB[row][col] = f2bf(silu_f(acc[mt][n2][r] + bb));
            }
        }
    }
    __syncthreads();

    // ----- pos layer 2 : tanh(hidden @ p2 + bp2) ; scatter wgt*rel_pos -----
    {
        const int r = tid >> 2, q = tid & 3;
        const u16* trow = &sB[r][q * 32];
        const u16* wrow = wp2 + q * 32;
        float p = 0.f;
#pragma unroll
        for (int k = 0; k < 32; ++k) p += bf2f(trow[k]) * bf2f(wrow[k]);
        p += __shfl_xor(p, 1);
        p += __shfl_xor(p, 2);
        if (q == 0) {
            float wgt = tanhf(p + bf2f(biasp2[0]));
            const size_t pb = ((size_t)sBat[r] * NN + sDst[r]) * 3;
            unsafeAtomicAdd(&pos_acc[pb + 0], wgt * sRel[r][0]);
            unsafeAtomicAdd(&pos_acc[pb + 1], wgt * sRel[r][1]);
            unsafeAtomicAdd(&pos_acc[pb + 2], wgt * sRel[r][2]);
        }
    }
}

__global__ __launch_bounds__(256) void update_kernel(
    const u16* __restrict__ feat, const void* __restrict__ rawfeat,
    const u16* __restrict__ dgu, const u16* __restrict__ dgd,
    const float* __restrict__ aggu, const float* __restrict__ aggd,
    const u16* __restrict__ fU1, const u16* __restrict__ bu1,
    const u16* __restrict__ fU2, const u16* __restrict__ bu2,
    void* __restrict__ outp, const int* __restrict__ flag)
{
    const int tid = threadIdx.x;
    const int lane = tid & 63;
    const int wv = tid >> 6;
    const int row0 = blockIdx.x * 64;   // node-instance rows
    const int isf = *flag;

    __shared__ u16 sA[64][136];   // features (bf16)
    __shared__ u16 sB[64][136];   // msg_acc (bf16)
    __shared__ u16 sY[64][136];   // hidden

    {
        const uint4* src = (const uint4*)(feat + (size_t)row0 * HH);
        for (int i = tid; i < 1024; i += 256) {
            int r = i >> 4, c = i & 15;
            *(uint4*)&sA[r][c * 8] = src[i];
        }
        const float4* au = (const float4*)(aggu) + (size_t)row0 * 32;
        const float4* ad = (const float4*)(aggd) + (size_t)row0 * 32;
        for (int i = tid; i < 2048; i += 256) {
            int r = i >> 5;
            int inst = row0 + r;
            int n = (inst >= NN) ? inst - NN : inst;
            float iu = 1.f / fmaxf(bf2f(dgu[n]), 1.f);
            float id = 1.f / fmaxf(bf2f(dgd[n]), 1.f);
            float4 u = au[i], d = ad[i];
            int c = (i & 31) * 4;
            sB[r][c + 0] = f2bf(u.x * iu + d.x * id);
            sB[r][c + 1] = f2bf(u.y * iu + d.y * id);
            sB[r][c + 2] = f2bf(u.z * iu + d.z * id);
            sB[r][c + 3] = f2bf(u.w * iu + d.w * id);
        }
    }
    __syncthreads();

    const int nt0 = wv * 2;
    const int mrow = lane & 15;
    const int kq = (lane >> 4) * 8;
    const int crow = (lane >> 4) * 4;
    const int ccol = lane & 15;

    f32x4 acc[4][2];
#pragma unroll
    for (int mt = 0; mt < 4; ++mt) {
        acc[mt][0] = (f32x4){0.f, 0.f, 0.f, 0.f};
        acc[mt][1] = (f32x4){0.f, 0.f, 0.f, 0.f};
    }
    // layer 1: [features | msg_acc] @ w_upd1 (K=256), silu
#pragma unroll
    for (int kt = 0; kt < 8; ++kt) {
        const u16* Xb = (kt < 4) ? &sA[0][0] : &sB[0][0];
        const int kk = (kt & 3) * 32 + kq;
        bf16x8 bw0 = *(const bf16x8*)(fU1 + (size_t)(((kt * 8 + nt0) * 64 + lane) * 8));
        bf16x8 bw1 = *(const bf16x8*)(fU1 + (size_t)(((kt * 8 + nt0 + 1) * 64 + lane) * 8));
#pragma unroll
        for (int mt = 0; mt < 4; ++mt) {
            bf16x8 a = *(const bf16x8*)(Xb + (mt * 16 + mrow) * 136 + kk);
            acc[mt][0] = MFMA(a, bw0, acc[mt][0]);
            acc[mt][1] = MFMA(a, bw1, acc[mt][1]);
        }
    }
#pragma unroll
    for (int mt = 0; mt < 4; ++mt) {
#pragma unroll
        for (int n2 = 0; n2 < 2; ++n2) {
            const int col = (nt0 + n2) * 16 + ccol;
            const float bb = bf2f(bu1[col]);
#pragma unroll
            for (int r = 0; r < 4; ++r) {
                const int row = mt * 16 + crow + r;
                sY[row][col] = f2bf(silu_f(acc[mt][n2][r] + bb));
            }
        }
    }
    __syncthreads();

    // layer 2 + residual -> out
#pragma unroll
    for (int mt = 0; mt < 4; ++mt) {
        acc[mt][0] = (f32x4){0.f, 0.f, 0.f, 0.f};
        acc[mt][1] = (f32x4){0.f, 0.f, 0.f, 0.f};
    }
#pragma unroll
    for (int kt = 0; kt < 4; ++kt) {
        const int kk = kt * 32 + kq;
        bf16x8 bw0 = *(const bf16x8*)(fU2 + (size_t)(((kt * 8 + nt0) * 64 + lane) * 8));
        bf16x8 bw1 = *(const bf16x8*)(fU2 + (size_t)(((kt * 8 + nt0 + 1) * 64 + lane) * 8));
#pragma unroll
        for (int mt = 0; mt < 4; ++mt) {
            bf16x8 a = *(const bf16x8*)(&sY[0][0] + (mt * 16 + mrow) * 136 + kk);
            acc[mt][0] = MFMA(a, bw0, acc[mt][0]);
            acc[mt][1] = MFMA(a, bw1, acc[mt][1]);
        }
    }
#pragma unroll
    for (int mt = 0; mt < 4; ++mt) {
#pragma unroll
        for (int n2 = 0; n2 < 2; ++n2) {
            const int col = (nt0 + n2) * 16 + ccol;
            const float bb = bf2f(bu2[col]);
#pragma unroll
            for (int r = 0; r < 4; ++r) {
                const int row = mt * 16 + crow + r;
                const size_t idx = (size_t)(row0 + row) * HH + col;
                if (isf) {
                    float base = ((const float*)rawfeat)[idx];
                    ((float*)outp)[idx] = acc[mt][n2][r] + bb + base;
                } else {
                    float base = bf2f(sA[row][col]);
                    ((u16*)outp)[idx] = f2bf(acc[mt][n2][r] + bb + base);
                }
            }
        }
    }
}

__global__ void pos_out_kernel(const void* __restrict__ rawpos, const u16* __restrict__ cpos,
                               const float* __restrict__ pacc, void* __restrict__ outp,
                               const int* __restrict__ flag)
{
    int i = blockIdx.x * 256 + threadIdx.x;
    if (i >= BB * NN * 3) return;
    if (*flag) {
        float base = ((const float*)rawpos)[i];
        ((float*)outp)[5120000 + i] = base + 0.5f * pacc[i];
    } else {
        float base = bf2f(cpos[i]);
        ((u16*)outp)[5120000 + i] = f2bf(base + 0.5f * pacc[i]);
    }
}

extern "C" void kernel_launch(void* const* d_in, const int* in_sizes, int n_in,
                              void* d_out, int out_size, void* d_ws, size_t ws_size,
                              hipStream_t stream)
{
    // workspace layout (bytes):
    //   [0, 41,440,000)            agg_up | agg_dn | pos_acc   (memset 0)
    //   [41,440,000, 41,800,448)   weight fragments (180,224 u16)
    //   [41,800,448, 52,724,000)   canonical bf16 inputs (5,461,776 u16)
    //   [52,724,000, +4)           dtype flag
    float* agg_up  = (float*)d_ws;
    float* agg_dn  = agg_up + 5120000;
    float* pos_acc = agg_dn + 5120000;
    const size_t ZERO_BYTES = 41440000;
    u16* fbase = (u16*)((char*)d_ws + ZERO_BYTES);
    u16* canon = (u16*)((char*)d_ws + 41800448);
    int* flag  = (int*)((char*)d_ws + 52724000);
    if (ws_size < 52724008ULL) return;

    u16* f_m1u = fbase;              // 32768 (K=256)
    u16* f_m2u = fbase + 32768;      // 16384 (K=128)
    u16* f_p1u = fbase + 49152;      // 16384
    u16* f_m1d = fbase + 65536;      // 32768
    u16* f_m2d = fbase + 98304;      // 16384
    u16* f_p1d = fbase + 114688;     // 16384
    u16* f_u1  = fbase + 131072;     // 32768
    u16* f_u2  = fbase + 163840;     // 16384

    // canonical tensor pointers
    u16* cfeat = canon;
    u16* cpos  = canon + 5120000;
    u16* cdgu  = canon + 5240000;
    u16* cdgd  = canon + 5260000;
    u16* cm1u  = canon + 5280000;
    u16* cbm1u = canon + 5312896;
    u16* cm2u  = canon + 5313024;
    u16* cbm2u = canon + 5329408;
    u16* cp1u  = canon + 5329536;
    u16* cbp1u = canon + 5345920;
    u16* cp2u  = canon + 5346048;
    u16* cbp2u = canon + 5346176;
    u16* cm1d  = canon + 5346184;
    u16* cbm1d = canon + 5379080;
    u16* cm2d  = canon + 5379208;
    u16* cbm2d = canon + 5395592;
    u16* cp1d  = canon + 5395720;
    u16* cbp1d = canon + 5412104;
    u16* cp2d  = canon + 5412232;
    u16* cbp2d = canon + 5412360;
    u16* cu1   = canon + 5412368;
    u16* cbu1  = canon + 5445136;
    u16* cu2   = canon + 5445264;
    u16* cbu2  = canon + 5461648;

    hipMemsetAsync(d_ws, 0, ZERO_BYTES, stream);

    detect_kernel<<<1, 256, 0, stream>>>((const u16*)d_in[0], flag);

    P24 ptrs;
    // order must match the canon offset table: feat,pos,dgu,dgd, then 8 up, 8 down, 4 upd
    ptrs.p[0] = d_in[0];  ptrs.p[1] = d_in[1];  ptrs.p[2] = d_in[4];  ptrs.p[3] = d_in[5];
    ptrs.p[4] = d_in[6];  ptrs.p[5] = d_in[7];  ptrs.p[6] = d_in[8];  ptrs.p[7] = d_in[9];
    ptrs.p[8] = d_in[10]; ptrs.p[9] = d_in[11]; ptrs.p[10] = d_in[12]; ptrs.p[11] = d_in[13];
    ptrs.p[12] = d_in[14]; ptrs.p[13] = d_in[15]; ptrs.p[14] = d_in[16]; ptrs.p[15] = d_in[17];
    ptrs.p[16] = d_in[18]; ptrs.p[17] = d_in[19]; ptrs.p[18] = d_in[20]; ptrs.p[19] = d_in[21];
    ptrs.p[20] = d_in[22]; ptrs.p[21] = d_in[23]; ptrs.p[22] = d_in[24]; ptrs.p[23] = d_in[25];
    canon_kernel<<<(CTOT + 255) / 256, 256, 0, stream>>>(ptrs, flag, canon);

    make_frag<<<128, 256, 0, stream>>>(cm1u, f_m1u);
    make_frag<<<64,  256, 0, stream>>>(cm2u, f_m2u);
    make_frag<<<64,  256, 0, stream>>>(cp1u, f_p1u);
    make_frag<<<128, 256, 0, stream>>>(cm1d, f_m1d);
    make_frag<<<64,  256, 0, stream>>>(cm2d, f_m2d);
    make_frag<<<64,  256, 0, stream>>>(cp1d, f_p1d);
    make_frag<<<128, 256, 0, stream>>>(cu1,  f_u1);
    make_frag<<<64,  256, 0, stream>>>(cu2,  f_u2);

    const int* ei_up = (const int*)d_in[2];
    const int* ei_dn = (const int*)d_in[3];

    edge_kernel<<<6250, 256, 0, stream>>>(
        cfeat, cpos, ei_up,
        f_m1u, cm1u + 256 * 128, cbm1u,
        f_m2u, cbm2u,
        f_p1u, cbp1u, cp2u, cbp2u,
        agg_up, pos_acc);
    edge_kernel<<<6250, 256, 0, stream>>>(
        cfeat, cpos, ei_dn,
        f_m1d, cm1d + 256 * 128, cbm1d,
        f_m2d, cbm2d,
        f_p1d, cbp1d, cp2d, cbp2d,
        agg_dn, pos_acc);

    update_kernel<<<625, 256, 0, stream>>>(
        cfeat, d_in[0], cdgu, cdgd, agg_up, agg_dn,
        f_u1, cbu1, f_u2, cbu2, d_out, flag);

    pos_out_kernel<<<469, 256, 0, stream>>>(d_in[1], cpos, pos_acc, d_out, flag);
}